// Round 6
// baseline (177.527 us; speedup 1.0000x reference)
//
#include <hip/hip_runtime.h>
#include <hip/hip_bf16.h>
#include <math.h>
#include <stdint.h>

#define B_ 64
#define L_ 2048
#define H_ 128
#define O_ 128
#define N_ 256
#define CH_ 128      // timesteps per chunk
#define NCH_ 16      // chunks
#define SPC_ 8       // strips (16 t) per chunk
#define CPB_ 4       // chunks per scan block (persistent pipeline)

using f32x4 = __attribute__((ext_vector_type(4))) float;
using i32x4 = __attribute__((ext_vector_type(4))) int;
using i32x2 = __attribute__((ext_vector_type(2))) int;
using h16x8 = __attribute__((ext_vector_type(8))) _Float16;

__device__ __forceinline__ unsigned short f16_bits(float v) {
    _Float16 h = (_Float16)v;                 // RNE convert
    return __builtin_bit_cast(unsigned short, h);
}
__device__ __forceinline__ int pack_f16(float a, float b) {
    return (int)((unsigned)f16_bits(a) | ((unsigned)f16_bits(b) << 16));
}

// ---------------------------------------------------------------------------
// prep: every block self-computes the nu-sorted permutation (rank 0 = slowest
// decay), then fills its slice of: B2Tr (fp16 (gamma*B)^T, rank-ordered cols),
// lamjR[rank][j]=lam^(15-j), lam16R=lam^16, lamCCr[c][rank]=lam^(128*(15-c)),
// nuR, perm, and zeroes X.
// ---------------------------------------------------------------------------
__global__ void prep_kernel(const float* __restrict__ nu_log, const float* __restrict__ theta_log,
                            const float* __restrict__ gamma_log, const float* __restrict__ B_re,
                            const float* __restrict__ B_im, unsigned short* __restrict__ B2Tr,
                            float2* __restrict__ lamjR, float2* __restrict__ lam16R,
                            float2* __restrict__ lamCCr, float* __restrict__ nuR,
                            int* __restrict__ perm, float* __restrict__ X) {
    __shared__ float nu_s[N_];
    __shared__ int perm_s[N_];
    const int t = threadIdx.x;
    float nu = expf(nu_log[t]);
    nu_s[t] = nu;
    __syncthreads();
    {
        int rank = 0;
        for (int j = 0; j < N_; ++j) {
            float vj = nu_s[j];
            rank += (vj < nu || (vj == nu && j < t)) ? 1 : 0;
        }
        perm_s[rank] = t;
    }
    __syncthreads();
    const int bb = blockIdx.x;
    if (bb < 64) {
        #pragma unroll
        for (int kk = 0; kk < 4; ++kk) {
            int e = bb * 1024 + kk * 256 + t;       // 0..65535
            int part = e >> 15, rank = (e >> 7) & 255, h = e & 127;
            int n = perm_s[rank];
            float g = expf(gamma_log[n]);
            float v = (part ? B_im : B_re)[n * H_ + h] * g;
            B2Tr[e] = f16_bits(v);
        }
    } else if (bb == 64) {
        int r = t, n = perm_s[r];
        float nun = nu_s[n];
        double th = (double)expf(theta_log[n]);
        double rr = exp(-(double)nun);
        double sn, cs;
        sincos(th, &sn, &cs);
        double lre = rr * cs, lim = rr * sn;
        double pre = 1.0, pim = 0.0;
        for (int k = 0; k < 16; ++k) {
            lamjR[r * 16 + 15 - k] = make_float2((float)pre, (float)pim);
            double t1 = pre * lre - pim * lim, t2 = pre * lim + pim * lre;
            pre = t1; pim = t2;
        }
        lam16R[r] = make_float2((float)pre, (float)pim);   // lam^16
        nuR[r] = nun;
        perm[r] = n;
        double wre = pre, wim = pim;                        // -> lam^128
        for (int i = 0; i < 3; ++i) {
            double a = wre * wre - wim * wim, b2 = 2.0 * wre * wim;
            wre = a; wim = b2;
        }
        double are = 1.0, aim = 0.0;
        for (int c = 15; c >= 0; --c) {
            lamCCr[c * N_ + r] = make_float2((float)are, (float)aim);
            double a = are * wre - aim * wim, b2 = are * wim + aim * wre;
            are = a; aim = b2;
        }
    } else {
        int idx = (bb - 65) * 1024 + t * 4;                 // 32 blocks x 1024 floats
        f32x4 z = {0.f, 0.f, 0.f, 0.f};
        *(f32x4*)&X[idx] = z;
    }
}

// ---------------------------------------------------------------------------
// scan (round 6): persistent-chunk register-double-buffered pipeline, all in
// ONE kernel (round 5's two-kernel staged-image split FAILED the harness's
// post-timing determinism check — cross-kernel global handoff of fresh data
// under graph replay is the suspect; reverted per G16, never hand fresh data
// between dispatches when avoidable).
// Grid: 256 blocks (1/CU), 512 threads. Block bx: b = bx&63, chunk group
// cg = bx>>6 -> chunks c = cg*4 .. cg*4+3 (256 KB contiguous u per block).
// Pipeline per iteration: {pack Lv->LDS (swizzled), barrier, ISSUE next
// chunk's 8 dwordx4/thread (in flight across compute), phase 2, barrier}.
// This converts the old one-shot 67 MB load burst (every resident block
// issued everything then sat in s_waitcnt; measured ~2.1 TB/s effective)
// into steady per-CU streaming like the 6.7 TB/s harness fills.
//  - wave g owns pairs {g, 15-g} (nu-rank balanced at hot chunks)
//  - strip alive iff nu*(base_e - 16s) <= 35 (e^-35 truncation)
//  - hottest cg=3 blocks land bx=192..255 -> spread over all 8 XCDs
// Phase 2 numerics byte-identical to round 4 (same pack, gates, lamCC
// rotation, one atomic pair per (pair, chunk)).
// ---------------------------------------------------------------------------
__global__ __launch_bounds__(512)
void scan_kernel(const float* __restrict__ u, const unsigned short* __restrict__ B2Tr,
                 const float2* __restrict__ lamjR, const float2* __restrict__ lam16R,
                 const float2* __restrict__ lamCCr, const float* __restrict__ nuR,
                 const int* __restrict__ perm, float* __restrict__ X) {
    const int bx = blockIdx.x;
    const int cg = bx >> 6;           // chunk group 0..3
    const int b = bx & 63;
    const int c0 = cg * CPB_;
    const int tid = threadIdx.x;

    __shared__ __align__(16) unsigned short Asm[CH_ * H_];   // 32 KB fp16 chunk image

    const float* gbase = u + ((size_t)b * L_ + (size_t)(c0 * CH_)) * H_;

    // ---- prologue: issue chunk c0 loads (contiguous 1 KB per wave instr) ----
    f32x4 Lv[8];
    #pragma unroll
    for (int k = 0; k < 8; ++k)
        Lv[k] = *(const f32x4*)(gbase + k * 2048 + tid * 4);

    // ---- wave-constant setup ----
    const int g = tid >> 6;                // wave 0..7
    const int lane = tid & 63;
    const int m = lane & 15, q = lane >> 4;
    const int p0 = g, p1 = 15 - g;         // balanced pair assignment
    const float nu0 = nuR[p0 * 16];
    const float nu1 = nuR[p1 * 16];
    const int c4 = tid & 31;               // 4-float granule within row
    const int gg = c4 >> 1;                // 8-float group 0..15
    const int half = c4 & 1;

    for (int cc = 0; cc < CPB_; ++cc) {
        const int c = c0 + cc;

        // ---- pack current chunk's registers into swizzled LDS image ----
        #pragma unroll
        for (int k = 0; k < 8; ++k) {
            const int r = k * 16 + (tid >> 5);                    // row 0..127
            i32x2 w;
            w[0] = pack_f16(Lv[k][0], Lv[k][1]);
            w[1] = pack_f16(Lv[k][2], Lv[k][3]);
            *(i32x2*)&Asm[r * H_ + ((gg ^ (r & 15)) * 8) + half * 4] = w;
        }
        __syncthreads();

        // ---- issue NEXT chunk's loads; they stream under phase 2 ----
        if (cc < CPB_ - 1) {
            const float* gnext = gbase + (size_t)(cc + 1) * (CH_ * H_);
            #pragma unroll
            for (int k = 0; k < 8; ++k)
                Lv[k] = *(const f32x4*)(gnext + k * 2048 + tid * 4);
        }

        // ---- phase 2: per-wave MFMA from LDS ----
        const float base_e = 2032.0f - 128.0f * (float)c;
        int spA = (int)ceilf((base_e - 35.0f / nu0) * 0.0625f);
        if (spA < 0) spA = 0;
        int spB = (int)ceilf((base_e - 35.0f / nu1) * 0.0625f);
        if (spB < 0) spB = 0;

        if (spA < SPC_) {                  // wave has live work (spA <= spB)
            #pragma unroll
            for (int p = 0; p < 2; ++p) {
                const int sp = p ? spB : spA;
                if (sp >= SPC_) continue;  // pair dead (wave-uniform)
                const int pp = p ? p1 : p0;
                const int rank = pp * 16 + m;

                h16x8 bfr[2][4];
                #pragma unroll
                for (int part = 0; part < 2; ++part) {
                    const unsigned short* rp = B2Tr + (size_t)(part * N_ + rank) * H_ + q * 8;
                    #pragma unroll
                    for (int sl = 0; sl < 4; ++sl)
                        bfr[part][sl] = *(const h16x8*)(rp + sl * 32);
                }
                float2 wl[4];
                #pragma unroll
                for (int r2 = 0; r2 < 4; ++r2) wl[r2] = lamjR[rank * 16 + q * 4 + r2];
                const float2 l16 = lam16R[rank];

                float2 zre = make_float2(0.f, 0.f), zim = make_float2(0.f, 0.f);
                for (int s = sp; s < SPC_; ++s) {
                    const int row = s * 16 + m;
                    h16x8 afr[4];
                    #pragma unroll
                    for (int sl = 0; sl < 4; ++sl) {
                        const int unit = (sl * 4 + q) ^ m;
                        afr[sl] = *(const h16x8*)&Asm[row * H_ + unit * 8];
                    }
                    // rescale accumulators by lam^16
                    float2 t0 = zre;
                    zre.x = l16.x * t0.x - l16.y * t0.y;
                    zre.y = l16.x * t0.y + l16.y * t0.x;
                    float2 t1 = zim;
                    zim.x = l16.x * t1.x - l16.y * t1.y;
                    zim.y = l16.x * t1.y + l16.y * t1.x;
                    f32x4 acc = {0.f, 0.f, 0.f, 0.f};
                    #pragma unroll
                    for (int sl = 0; sl < 4; ++sl)
                        acc = __builtin_amdgcn_mfma_f32_16x16x32_f16(afr[sl], bfr[0][sl], acc, 0, 0, 0);
                    #pragma unroll
                    for (int r2 = 0; r2 < 4; ++r2) {
                        zre.x += wl[r2].x * acc[r2];
                        zre.y += wl[r2].y * acc[r2];
                    }
                    f32x4 acc2 = {0.f, 0.f, 0.f, 0.f};
                    #pragma unroll
                    for (int sl = 0; sl < 4; ++sl)
                        acc2 = __builtin_amdgcn_mfma_f32_16x16x32_f16(afr[sl], bfr[1][sl], acc2, 0, 0, 0);
                    #pragma unroll
                    for (int r2 = 0; r2 < 4; ++r2) {
                        zim.x += wl[r2].x * acc2[r2];
                        zim.y += wl[r2].y * acc2[r2];
                    }
                }

                // reduce over q, rotate by lamCC, atomic complex partials
                float a = zre.x, b2 = zre.y, c2 = zim.x, d2 = zim.y;
                a  += __shfl_xor(a, 16);  a  += __shfl_xor(a, 32);
                b2 += __shfl_xor(b2, 16); b2 += __shfl_xor(b2, 32);
                c2 += __shfl_xor(c2, 16); c2 += __shfl_xor(c2, 32);
                d2 += __shfl_xor(d2, 16); d2 += __shfl_xor(d2, 32);
                if (lane < 16) {
                    const int n = perm[rank];
                    float2 lc = lamCCr[c * N_ + rank];
                    float prr = lc.x * a - lc.y * b2;
                    float pri = lc.x * b2 + lc.y * a;
                    float pir = lc.x * c2 - lc.y * d2;
                    float pii = lc.x * d2 + lc.y * c2;
                    atomicAdd(&X[(size_t)(b * N_ + n) * 2 + 0], prr - pii);
                    atomicAdd(&X[(size_t)(b * N_ + n) * 2 + 1], pri + pir);
                }
            }
        }
        __syncthreads();                   // phase-2 reads done before next pack
    }
}

// ---------------------------------------------------------------------------
// out: y[b,o] = sum_n (Cre*Xre - Cim*Xim) + sum_h D[o,h]*u[b,L-1,h]
// 512 threads, 4 threads per o, f32x4 loads, __shfl_xor(1,2) reduce.
// (old 256-thread serial-dot version was 14.9 us at 1.7% occupancy)
// ---------------------------------------------------------------------------
__global__ __launch_bounds__(512)
void out_kernel(const float* __restrict__ X, const float* __restrict__ C_re,
                const float* __restrict__ C_im, const float* __restrict__ Dm,
                const float* __restrict__ u, float* __restrict__ out) {
    __shared__ __align__(16) float xre[N_];
    __shared__ __align__(16) float xim[N_];
    __shared__ __align__(16) float ul[H_];
    const int b = blockIdx.x;
    const int t = threadIdx.x;
    if (t < N_) {
        float2 x2 = *(const float2*)&X[(size_t)(b * N_ + t) * 2];
        xre[t] = x2.x;
        xim[t] = x2.y;
    }
    if (t < H_) ul[t] = u[((size_t)b * L_ + (L_ - 1)) * H_ + t];
    __syncthreads();
    const int o = t >> 2;              // 128 outputs
    const int part = t & 3;            // quarter of the reduction
    const float* cre = C_re + o * N_ + part * 64;
    const float* cim = C_im + o * N_ + part * 64;
    const float* xr  = xre + part * 64;
    const float* xi  = xim + part * 64;
    float s = 0.f;
    #pragma unroll
    for (int i = 0; i < 16; ++i) {
        f32x4 cr = *(const f32x4*)(cre + i * 4);
        f32x4 ci = *(const f32x4*)(cim + i * 4);
        f32x4 vr = *(const f32x4*)(xr + i * 4);
        f32x4 vi = *(const f32x4*)(xi + i * 4);
        s += cr[0] * vr[0] - ci[0] * vi[0];
        s += cr[1] * vr[1] - ci[1] * vi[1];
        s += cr[2] * vr[2] - ci[2] * vi[2];
        s += cr[3] * vr[3] - ci[3] * vi[3];
    }
    const float* dp = Dm + o * H_ + part * 32;
    const float* up = ul + part * 32;
    #pragma unroll
    for (int i = 0; i < 8; ++i) {
        f32x4 d4 = *(const f32x4*)(dp + i * 4);
        f32x4 u4 = *(const f32x4*)(up + i * 4);
        s += d4[0] * u4[0] + d4[1] * u4[1] + d4[2] * u4[2] + d4[3] * u4[3];
    }
    s += __shfl_xor(s, 1);
    s += __shfl_xor(s, 2);
    if (part == 0) out[b * O_ + o] = s;
}

extern "C" void kernel_launch(void* const* d_in, const int* in_sizes, int n_in,
                              void* d_out, int out_size, void* d_ws, size_t ws_size,
                              hipStream_t stream) {
    const float* u         = (const float*)d_in[2];   // dynamics_disturbance_time_window
    const float* nu_log    = (const float*)d_in[3];
    const float* theta_log = (const float*)d_in[4];
    const float* gamma_log = (const float*)d_in[5];
    const float* B_re      = (const float*)d_in[6];
    const float* B_im      = (const float*)d_in[7];
    const float* C_re      = (const float*)d_in[8];
    const float* C_im      = (const float*)d_in[9];
    const float* Dm        = (const float*)d_in[10];

    char* ws = (char*)d_ws;
    float*          X      = (float*)ws;                       // 131072 B
    unsigned short* B2Tr   = (unsigned short*)(ws + 131072);   // 131072 B
    float2*         lamjR  = (float2*)(ws + 262144);           // 32768 B
    float2*         lam16R = (float2*)(ws + 294912);           // 2048 B
    float2*         lamCCr = (float2*)(ws + 296960);           // 32768 B
    float*          nuR    = (float*)(ws + 329728);            // 1024 B
    int*            perm   = (int*)(ws + 330752);              // 1024 B

    prep_kernel<<<97, 256, 0, stream>>>(nu_log, theta_log, gamma_log, B_re, B_im,
                                        B2Tr, lamjR, lam16R, lamCCr, nuR, perm, X);
    scan_kernel<<<B_ * NCH_ / CPB_, 512, 0, stream>>>(u, B2Tr, lamjR, lam16R, lamCCr, nuR, perm, X);
    out_kernel<<<B_, 512, 0, stream>>>(X, C_re, C_im, Dm, u, (float*)d_out);
}